// Round 2
// baseline (2556.576 us; speedup 1.0000x reference)
//
#include <hip/hip_runtime.h>
#include <math.h>

// Problem constants
#define PIX   16384       // H*W = 128*128
#define NB    8           // batch
#define CIN   256

__device__ __forceinline__ float gelu_f(float v) {
  return 0.5f * v * (1.f + erff(v * 0.70710678118654752f));
}

// ---------------------------------------------------------------- zero
__global__ void zero_kernel(float* p, int n) {
  int i = blockIdx.x * blockDim.x + threadIdx.x;
  if (i < n) p[i] = 0.f;
}

// ----------------------------------------------------- weight transpose
// mlp_w0 (512,512) [k][o] -> w0t (512,512) [o][k]
// mlp_w1 (512,256) [k][o] -> w1t (256,512) [o][k]
__global__ void transpose_w(const float* __restrict__ w0, const float* __restrict__ w1,
                            float* __restrict__ w0t, float* __restrict__ w1t) {
  int i = blockIdx.x * 256 + threadIdx.x;
  if (i < 512 * 512) {
    int o = i >> 9, k = i & 511;
    w0t[i] = w0[k * 512 + o];
  } else {
    int j = i - 512 * 512;
    int o = j >> 9, k = j & 511;
    w1t[j] = w1[k * 256 + o];
  }
}

// ------------------------------------------------------------------ GEMM
// Y[n,o,p] = sum_k Wm[o,k] * X[n,k,p] + bias[o]   (optional gelu)
// CONCAT: X rows k<K1 from X1, rows >=K1 from X2 with per-(n,row) affine
// (folds groupnorm0 into the MLP0 input load). n is chunk-local.
// Tile: 64 o x 128 p, BK=32, 256 threads, 4x8 microtile.
template <bool CONCAT, bool GELU>
__global__ __launch_bounds__(256) void gemm_kernel(
    const float* __restrict__ Wm, const float* __restrict__ bias,
    const float* __restrict__ X1, const float* __restrict__ X2,
    const float* __restrict__ scl, const float* __restrict__ bia,
    float* __restrict__ Y, int O, int K, int K1) {
  __shared__ float Ws[32][68];    // [k][o], pad 68 to spread banks
  __shared__ float Xs[32][132];   // [k][p], pad 132

  const int t  = threadIdx.x;
  const int n  = blockIdx.z;
  const int p0 = blockIdx.x * 128;
  const int o0 = blockIdx.y * 64;
  const int to = t >> 4, tp = t & 15;        // compute 4 o x (4+4) p
  const int wo = t >> 2, wk = (t & 3) * 8;   // W staging: row o, 8 k
  const int xk = t >> 3, xp = (t & 7) * 16;  // X staging: row k, 16 p
  const int K2 = K - K1;

  float acc[4][8];
#pragma unroll
  for (int i = 0; i < 4; i++)
#pragma unroll
    for (int j = 0; j < 8; j++) acc[i][j] = 0.f;

  const float* Wrow = Wm + (size_t)(o0 + wo) * K + wk;

  for (int k0 = 0; k0 < K; k0 += 32) {
    float4 wv0 = *(const float4*)(Wrow + k0);
    float4 wv1 = *(const float4*)(Wrow + k0 + 4);

    const int kg = k0 + xk;
    const float* Xrow;
    float sA = 1.f, sB = 0.f;
    if (!CONCAT || kg < K1) {
      Xrow = X1 + ((size_t)n * K1 + kg) * PIX + p0 + xp;
    } else {
      int k2 = kg - K1;
      Xrow = X2 + ((size_t)n * K2 + k2) * PIX + p0 + xp;
      sA = scl[n * K2 + k2];
      sB = bia[n * K2 + k2];
    }
    float4 xv0 = *(const float4*)(Xrow);
    float4 xv1 = *(const float4*)(Xrow + 4);
    float4 xv2 = *(const float4*)(Xrow + 8);
    float4 xv3 = *(const float4*)(Xrow + 12);
    if (CONCAT && kg >= K1) {
      xv0.x = fmaf(xv0.x, sA, sB); xv0.y = fmaf(xv0.y, sA, sB);
      xv0.z = fmaf(xv0.z, sA, sB); xv0.w = fmaf(xv0.w, sA, sB);
      xv1.x = fmaf(xv1.x, sA, sB); xv1.y = fmaf(xv1.y, sA, sB);
      xv1.z = fmaf(xv1.z, sA, sB); xv1.w = fmaf(xv1.w, sA, sB);
      xv2.x = fmaf(xv2.x, sA, sB); xv2.y = fmaf(xv2.y, sA, sB);
      xv2.z = fmaf(xv2.z, sA, sB); xv2.w = fmaf(xv2.w, sA, sB);
      xv3.x = fmaf(xv3.x, sA, sB); xv3.y = fmaf(xv3.y, sA, sB);
      xv3.z = fmaf(xv3.z, sA, sB); xv3.w = fmaf(xv3.w, sA, sB);
    }

    __syncthreads();  // previous tile fully consumed
    {
      const float wvals[8] = {wv0.x, wv0.y, wv0.z, wv0.w, wv1.x, wv1.y, wv1.z, wv1.w};
#pragma unroll
      for (int q = 0; q < 8; q++) Ws[wk + q][wo] = wvals[q];
    }
    *(float4*)&Xs[xk][xp]      = xv0;
    *(float4*)&Xs[xk][xp + 4]  = xv1;
    *(float4*)&Xs[xk][xp + 8]  = xv2;
    *(float4*)&Xs[xk][xp + 12] = xv3;
    __syncthreads();

#pragma unroll 8
    for (int kk = 0; kk < 32; kk++) {
      const float4 a   = *(const float4*)&Ws[kk][to * 4];
      const float4 b0v = *(const float4*)&Xs[kk][tp * 4];
      const float4 b1v = *(const float4*)&Xs[kk][64 + tp * 4];
      const float av[4] = {a.x, a.y, a.z, a.w};
      const float bv[8] = {b0v.x, b0v.y, b0v.z, b0v.w, b1v.x, b1v.y, b1v.z, b1v.w};
#pragma unroll
      for (int i = 0; i < 4; i++)
#pragma unroll
        for (int j = 0; j < 8; j++) acc[i][j] = fmaf(av[i], bv[j], acc[i][j]);
    }
  }

#pragma unroll
  for (int i = 0; i < 4; i++) {
    const int o = o0 + to * 4 + i;
    const float bo = bias[o];
    float4 r0, r1;
    float v;
    v = acc[i][0] + bo; if (GELU) v = gelu_f(v); r0.x = v;
    v = acc[i][1] + bo; if (GELU) v = gelu_f(v); r0.y = v;
    v = acc[i][2] + bo; if (GELU) v = gelu_f(v); r0.z = v;
    v = acc[i][3] + bo; if (GELU) v = gelu_f(v); r0.w = v;
    v = acc[i][4] + bo; if (GELU) v = gelu_f(v); r1.x = v;
    v = acc[i][5] + bo; if (GELU) v = gelu_f(v); r1.y = v;
    v = acc[i][6] + bo; if (GELU) v = gelu_f(v); r1.z = v;
    v = acc[i][7] + bo; if (GELU) v = gelu_f(v); r1.w = v;
    float* yrow = Y + ((size_t)n * O + o) * PIX + p0;
    *(float4*)(yrow + tp * 4)      = r0;
    *(float4*)(yrow + 64 + tp * 4) = r1;
  }
}

// ------------------------------------------------------------- cluster
// One block per m = (n_local, f, s1, s2). Everything (centers, l2norm, sim,
// argmax, weighted scatter-mean, gather) is m-local -> LDS only.
// y layout: (c, 512, 128,128); m's channels = f*64..f*64+63,
// m's quadrant = rows s1*64.., cols s2*64..
__global__ __launch_bounds__(256) void cluster_kernel(
    const float* __restrict__ y, const float* __restrict__ alpha_p,
    const float* __restrict__ beta_p, float* __restrict__ nx) {
  const int m = blockIdx.x;
  const int n = m >> 5, f = (m >> 2) & 7, s1 = (m >> 1) & 1, s2 = m & 1;
  const int t = threadIdx.x;
  const float alpha = alpha_p[0], beta = beta_p[0];

  __shared__ float cs[64][64];            // [cc][b] center means (16 KB)
  __shared__ float cpn[64][36];           // [b][cc] l2-normed point-centers
  __shared__ float acc[64][33];           // cluster accumulators (+count)
  __shared__ float svals[4096];           // per-point max sim
  __shared__ unsigned char sbest[4096];   // per-point argmax center

  const size_t chbase = ((size_t)(n * 512 + f * 64)) << 14;
  const int pixbase = s1 * 64 * 128 + s2 * 64;
  const float* ybase = y + chbase + pixbase;

  // ---- phase 1: 8x8 block means -> centers (all 64 channels)
  for (int idx = t; idx < 4096; idx += 256) {
    int cc = idx >> 6, b = idx & 63;
    const float* p = ybase + ((size_t)cc << 14) + (b >> 3) * (8 * 128) + (b & 7) * 8;
    float ssum = 0.f;
#pragma unroll
    for (int r = 0; r < 8; r++) {
      float4 v0 = *(const float4*)(p + r * 128);
      float4 v1 = *(const float4*)(p + r * 128 + 4);
      ssum += (v0.x + v0.y) + (v0.z + v0.w) + (v1.x + v1.y) + (v1.z + v1.w);
    }
    cs[cc][b] = ssum * (1.f / 64.f);
  }
  __syncthreads();

  // ---- phase 1b: normalize point-half of centers, init accumulators
  if (t < 64) {
    const int b = t;
    float s = 0.f;
#pragma unroll
    for (int cc = 0; cc < 32; cc++) { float v = cs[cc][b]; s = fmaf(v, v, s); }
    float inv = 1.f / fmaxf(sqrtf(s), 1e-12f);
#pragma unroll
    for (int cc = 0; cc < 32; cc++) cpn[b][cc] = cs[cc][b] * inv;
#pragma unroll
    for (int q = 0; q < 32; q++) acc[b][q] = cs[32 + q][b];
    acc[b][32] = 1.f;
  }
  __syncthreads();

  // ---- phase 2: per-point best center + weighted scatter (2 pts/iter)
#pragma unroll 1
  for (int g = 0; g < 8; g++) {
    const int la = g * 512 + t;
    const int lb = la + 256;
    const int pa = ((la >> 6) * 128) + (la & 63);
    const int pb = ((lb >> 6) * 128) + (lb & 63);
    float xpa[32], xpb[32];
#pragma unroll
    for (int cc = 0; cc < 32; cc++) {
      xpa[cc] = ybase[((size_t)cc << 14) + pa];
      xpb[cc] = ybase[((size_t)cc << 14) + pb];
    }
    float na = 0.f, nbv = 0.f;
#pragma unroll
    for (int cc = 0; cc < 32; cc++) {
      na  = fmaf(xpa[cc], xpa[cc], na);
      nbv = fmaf(xpb[cc], xpb[cc], nbv);
    }
    const float inva = 1.f / fmaxf(sqrtf(na), 1e-12f);
    const float invb = 1.f / fmaxf(sqrtf(nbv), 1e-12f);
    float zma = -1e30f, zmb = -1e30f;
    int bba = 0, bbb = 0;
    for (int b = 0; b < 64; b++) {
      float da = 0.f, db = 0.f;
#pragma unroll
      for (int c4 = 0; c4 < 32; c4 += 4) {
        const float4 cp = *(const float4*)&cpn[b][c4];
        da = fmaf(xpa[c4], cp.x, da); da = fmaf(xpa[c4 + 1], cp.y, da);
        da = fmaf(xpa[c4 + 2], cp.z, da); da = fmaf(xpa[c4 + 3], cp.w, da);
        db = fmaf(xpb[c4], cp.x, db); db = fmaf(xpb[c4 + 1], cp.y, db);
        db = fmaf(xpb[c4 + 2], cp.z, db); db = fmaf(xpb[c4 + 3], cp.w, db);
      }
      float za = fmaf(alpha, da * inva, beta);
      float zb = fmaf(alpha, db * invb, beta);
      if (za > zma) { zma = za; bba = b; }   // strict > : first max (argmax)
      if (zb > zmb) { zmb = zb; bbb = b; }
    }
    const float va = 1.f / (1.f + __expf(-zma));  // sigmoid(max z)
    const float vb = 1.f / (1.f + __expf(-zmb));
    svals[la] = va; sbest[la] = (unsigned char)bba;
    svals[lb] = vb; sbest[lb] = (unsigned char)bbb;
#pragma unroll
    for (int q = 0; q < 32; q++) {
      float wa = ybase[((size_t)(32 + q) << 14) + pa];
      float wb = ybase[((size_t)(32 + q) << 14) + pb];
      atomicAdd(&acc[bba][q], va * wa);
      atomicAdd(&acc[bbb][q], vb * wb);
    }
    atomicAdd(&acc[bba][32], va);
    atomicAdd(&acc[bbb][32], vb);
  }
  __syncthreads();

  // ---- phase 3: cluster means (count >= 1, no div-by-zero)
  for (int idx = t; idx < 2048; idx += 256) {
    int b = idx >> 5, q = idx & 31;
    acc[b][q] = acc[b][q] / acc[b][32];
  }
  __syncthreads();

  // ---- phase 4: gather back, write nx (channels f*32..f*32+31)
  float* nxb = nx + (((size_t)(n * 256 + f * 32)) << 14) + pixbase;
#pragma unroll 1
  for (int i = 0; i < 16; i++) {
    const int l = i * 256 + t;
    const int pp = ((l >> 6) * 128) + (l & 63);
    const float v = svals[l];
    const int b = sbest[l];
#pragma unroll
    for (int q = 0; q < 32; q++) nxb[((size_t)q << 14) + pp] = v * acc[b][q];
  }
}

// ------------------------------------------------------ groupnorm reduce
// per-n sum & sumsq over C*P elements -> sums[2n], sums[2n+1] (n chunk-local)
__global__ __launch_bounds__(256) void gn_reduce(const float* __restrict__ v,
                                                 float* __restrict__ sums) {
  const int n = blockIdx.y;
  const float4* base = (const float4*)(v + ((size_t)n << 22));
  float s = 0.f, s2 = 0.f;
  const int total4 = (CIN * PIX) / 4;
  for (int i = blockIdx.x * 256 + threadIdx.x; i < total4; i += 64 * 256) {
    float4 x = base[i];
    s += (x.x + x.y) + (x.z + x.w);
    s2 = fmaf(x.x, x.x, s2); s2 = fmaf(x.y, x.y, s2);
    s2 = fmaf(x.z, x.z, s2); s2 = fmaf(x.w, x.w, s2);
  }
  for (int off = 32; off > 0; off >>= 1) {
    s += __shfl_down(s, off);
    s2 += __shfl_down(s2, off);
  }
  __shared__ float ws1[4], ws2[4];
  const int wid = threadIdx.x >> 6, lane = threadIdx.x & 63;
  if (lane == 0) { ws1[wid] = s; ws2[wid] = s2; }
  __syncthreads();
  if (threadIdx.x == 0) {
    atomicAdd(&sums[2 * n],     ws1[0] + ws1[1] + ws1[2] + ws1[3]);
    atomicAdd(&sums[2 * n + 1], ws2[0] + ws2[1] + ws2[2] + ws2[3]);
  }
}

// per-(n,c) affine for folding GN0 into MLP0's X load
__global__ void gn_finalize0(const float* __restrict__ sums, const float* __restrict__ g0w,
                             const float* __restrict__ g0b, float* __restrict__ scl,
                             float* __restrict__ bia) {
  const int n = blockIdx.x, c = threadIdx.x;
  const float cntinv = 1.f / (float)(CIN * PIX);
  float mu = sums[2 * n] * cntinv;
  float var = sums[2 * n + 1] * cntinv - mu * mu;
  float rs = rsqrtf(var + 1e-5f);
  float a = rs * g0w[c];
  scl[n * 256 + c] = a;
  bia[n * 256 + c] = g0b[c] - mu * a;
}

// --------------------------------------------------------------- final
// out = GN1(u)*layer_scale + x   (n chunk-local)
__global__ __launch_bounds__(256) void final_kernel(
    const float* __restrict__ u, const float* __restrict__ x,
    const float* __restrict__ sums, const float* __restrict__ g1w,
    const float* __restrict__ g1b, const float* __restrict__ lsc,
    float* __restrict__ out) {
  const int i4 = blockIdx.x * 256 + threadIdx.x;
  const int idx = i4 << 2;
  const int n = idx >> 22;
  const int c = (idx >> 14) & 255;
  const float cntinv = 1.f / (float)(CIN * PIX);
  float mu = sums[2 * n] * cntinv;
  float var = sums[2 * n + 1] * cntinv - mu * mu;
  float rs = rsqrtf(var + 1e-5f);
  float a = rs * g1w[c] * lsc[c];
  float bb = (g1b[c] - mu * rs * g1w[c]) * lsc[c];
  float4 uv = ((const float4*)u)[i4];
  float4 xv = ((const float4*)x)[i4];
  float4 o;
  o.x = fmaf(uv.x, a, bb) + xv.x;
  o.y = fmaf(uv.y, a, bb) + xv.y;
  o.z = fmaf(uv.z, a, bb) + xv.z;
  o.w = fmaf(uv.w, a, bb) + xv.w;
  ((float4*)out)[i4] = o;
}

// ---------------------------------------------------------------- launch
extern "C" void kernel_launch(void* const* d_in, const int* in_sizes, int n_in,
                              void* d_out, int out_size, void* d_ws, size_t ws_size,
                              hipStream_t stream) {
  const float* x       = (const float*)d_in[0];
  const float* proj_w  = (const float*)d_in[1];
  const float* proj_b  = (const float*)d_in[2];
  const float* merge_w = (const float*)d_in[3];
  const float* merge_b = (const float*)d_in[4];
  const float* alpha   = (const float*)d_in[5];
  const float* beta    = (const float*)d_in[6];
  const float* g0w     = (const float*)d_in[7];
  const float* g0b     = (const float*)d_in[8];
  const float* w0      = (const float*)d_in[9];
  const float* b0      = (const float*)d_in[10];
  const float* w1      = (const float*)d_in[11];
  const float* b1      = (const float*)d_in[12];
  const float* g1w     = (const float*)d_in[13];
  const float* g1b     = (const float*)d_in[14];
  const float* lsc     = (const float*)d_in[15];
  float* out = (float*)d_out;

  // Choose batch-chunk size c from ws_size (deterministic -> capture-safe).
  // Per image: y/h = 512*16384 floats (32 MiB), nx/u = 256*16384 (16 MiB).
  // newx lives in d_out's chunk region (dead before final writes it).
  const size_t ws_floats = ws_size / sizeof(float);
  int c = 8;
  while (c > 1) {
    size_t need = (size_t)c * (8388608 + 4194304 + 512) + 262144 + 131072 + 64;
    if (need <= ws_floats) break;
    c >>= 1;
  }

  float* ws    = (float*)d_ws;
  float* y_ws  = ws;                                  // c * 8388608 (reused as h)
  float* nx_ws = y_ws + (size_t)c * 8388608;          // c * 4194304 (reused as u)
  float* w0t   = nx_ws + (size_t)c * 4194304;         // 262144
  float* w1t   = w0t + 262144;                        // 131072
  float* sums  = w1t + 131072;                        // 32: gn0 [0..15], gn1 [16..31]
  float* scl0  = sums + 32;                           // c*256
  float* bia0  = scl0 + (size_t)c * 256;              // c*256

  transpose_w<<<1536, 256, 0, stream>>>(w0, w1, w0t, w1t);

  for (int n0 = 0; n0 < NB; n0 += c) {
    const float* x_c   = x + (size_t)n0 * CIN * PIX;
    float*       out_c = out + (size_t)n0 * CIN * PIX;
    float*       newx  = out_c;   // scratch inside the output chunk

    zero_kernel<<<1, 64, 0, stream>>>(sums, 32);

    // proj: y = proj_w @ x + proj_b
    gemm_kernel<false, false><<<dim3(128, 8, c), 256, 0, stream>>>(
        proj_w, proj_b, x_c, nullptr, nullptr, nullptr, y_ws, 512, 256, 256);

    // cluster: y -> nx
    cluster_kernel<<<c * 32, 256, 0, stream>>>(y_ws, alpha, beta, nx_ws);

    // merge: newx = merge_w @ nx + merge_b
    gemm_kernel<false, false><<<dim3(128, 4, c), 256, 0, stream>>>(
        merge_w, merge_b, nx_ws, nullptr, nullptr, nullptr, newx, 256, 256, 256);

    // GN0 stats + per-(n,c) affine (folded into MLP0 X load)
    gn_reduce<<<dim3(64, c), 256, 0, stream>>>(newx, sums);
    gn_finalize0<<<c, 256, 0, stream>>>(sums, g0w, g0b, scl0, bia0);

    // MLP0: h = gelu([x ; gn0(newx)] @ w0 + b0)   (h reuses y_ws)
    gemm_kernel<true, true><<<dim3(128, 8, c), 256, 0, stream>>>(
        w0t, b0, x_c, newx, scl0, bia0, y_ws, 512, 512, 256);

    // MLP1: u = h @ w1 + b1   (u reuses nx_ws)
    gemm_kernel<false, false><<<dim3(128, 4, c), 256, 0, stream>>>(
        w1t, b1, y_ws, nullptr, nullptr, nullptr, nx_ws, 256, 512, 512);

    // GN1 stats + final: out = gn1(u)*ls + x  (overwrites newx scratch)
    gn_reduce<<<dim3(64, c), 256, 0, stream>>>(nx_ws, sums + 16);
    final_kernel<<<c * 4096, 256, 0, stream>>>(nx_ws, x_c, sums + 16, g1w, g1b, lsc, out_c);
  }
}

// Round 3
// 1080.511 us; speedup vs baseline: 2.3661x; 2.3661x over previous
//
#include <hip/hip_runtime.h>
#include <math.h>

#define PIX   16384       // H*W
#define NB    8
#define CIN   256

typedef __attribute__((ext_vector_type(8))) short    short8;   // bf16x8 frag (4 VGPR)
typedef __attribute__((ext_vector_type(4))) float    f32x4;
typedef __attribute__((ext_vector_type(4))) unsigned short us4;
typedef __attribute__((ext_vector_type(8))) unsigned short us8;

__device__ __forceinline__ float bf2f(unsigned short h) {
  return __uint_as_float(((unsigned int)h) << 16);
}
__device__ __forceinline__ unsigned short f2bf(float f) {  // round-nearest-even
  unsigned int u = __float_as_uint(f);
  return (unsigned short)((u + 0x7FFFu + ((u >> 16) & 1u)) >> 16);
}
__device__ __forceinline__ float gelu_f(float v) {
  return 0.5f * v * (1.f + erff(v * 0.70710678118654752f));
}

// ---------------------------------------------------------------- zero
__global__ void zero_kernel(float* p, int n) {
  int i = blockIdx.x * blockDim.x + threadIdx.x;
  if (i < n) p[i] = 0.f;
}

// ---------------------------------------------------- weight prep (bf16)
// pw  = bf16(proj_w)  [512][256]   (already [o][k])
// mw  = bf16(merge_w) [256][256]   (already [o][k])
// w0t = bf16(w0^T)    [512][512]   (w0 is [k][o])
// w1t = bf16(w1^T)    [256][512]   (w1 is [k][o])
__global__ void prep_weights(const float* __restrict__ pw_f, const float* __restrict__ mw_f,
                             const float* __restrict__ w0, const float* __restrict__ w1,
                             unsigned short* __restrict__ pw, unsigned short* __restrict__ mw,
                             unsigned short* __restrict__ w0t, unsigned short* __restrict__ w1t) {
  const int S1 = 512 * 256, S2 = 256 * 256, S3 = 512 * 512, S4 = 256 * 512;
  int i = blockIdx.x * 256 + threadIdx.x;
  if (i < S1) { pw[i] = f2bf(pw_f[i]); return; }
  i -= S1;
  if (i < S2) { mw[i] = f2bf(mw_f[i]); return; }
  i -= S2;
  if (i < S3) { int o = i >> 9, k = i & 511; w0t[i] = f2bf(w0[k * 512 + o]); return; }
  i -= S3;
  if (i < S4) { int o = i >> 9, k = i & 511; w1t[i] = f2bf(w1[k * 256 + o]); }
}

// ------------------------------------------- x: NCHW fp32 -> NHWC bf16
__global__ __launch_bounds__(256) void x_to_nhwc(const float* __restrict__ x,
                                                 unsigned short* __restrict__ xT) {
  __shared__ float tile[64][65];
  const int t = threadIdx.x;
  const int p0 = blockIdx.x * 64, c0 = blockIdx.y * 64, n = blockIdx.z;
#pragma unroll
  for (int i = 0; i < 4; i++) {
    const int c = i * 16 + (t >> 4);
    const float4 v = *(const float4*)(x + ((size_t)(n * 256 + c0 + c) << 14) + p0 + (t & 15) * 4);
    tile[c][(t & 15) * 4]     = v.x;
    tile[c][(t & 15) * 4 + 1] = v.y;
    tile[c][(t & 15) * 4 + 2] = v.z;
    tile[c][(t & 15) * 4 + 3] = v.w;
  }
  __syncthreads();
#pragma unroll
  for (int i = 0; i < 4; i++) {
    const int pp = i * 16 + (t >> 4);
    const int cl = (t & 15) * 4;
    us4 o;
    o.x = f2bf(tile[cl][pp]); o.y = f2bf(tile[cl + 1][pp]);
    o.z = f2bf(tile[cl + 2][pp]); o.w = f2bf(tile[cl + 3][pp]);
    *(us4*)&xT[(((size_t)n << 14) + p0 + pp) * 256 + c0 + cl] = o;
  }
}

// ---------------------------------------------------------- MFMA GEMM
// Y[n][p][o] = sum_k A[o][k] * B[n][p][k] + bias[o]  (optional gelu)
// A bf16 [M][K]; B bf16 [n][PIX][K1] (+B2 [n][PIX][K2] for k>=K1 when CONCAT).
// 256 thr = 4 waves; 128(M=o) x 128(N=p) tile; BK=64; 16x16x32 bf16 MFMA.
// LDS staged in fragment order via global_load_lds(16B): chunk c (1KB) holds
// tile (tm=c>>1, kk=c&1): lane -> row (lane&15), k = kk*32+(lane>>4)*8.
template<bool CONCAT, bool GELU>
__global__ __launch_bounds__(256, 2) void mfma_gemm(
    const unsigned short* __restrict__ A, const float* __restrict__ bias,
    const unsigned short* __restrict__ B1, const unsigned short* __restrict__ B2,
    unsigned short* __restrict__ Y, int M, int K, int K1) {
  __shared__ unsigned short As[8192];
  __shared__ unsigned short Bs[8192];
  const int t = threadIdx.x;
  const int lane = t & 63, w = t >> 6;
  const int quad = lane >> 4, l16 = lane & 15;
  const int p0 = blockIdx.x * 128, m0 = blockIdx.y * 128;
  const int n = blockIdx.z;
  const int wm = w & 1, wn = w >> 1;
  const int K2 = K - K1;

  f32x4 acc[4][4];
#pragma unroll
  for (int im = 0; im < 4; im++)
#pragma unroll
    for (int in = 0; in < 4; in++) acc[im][in] = (f32x4)0.f;

  for (int k0 = 0; k0 < K; k0 += 64) {
    __syncthreads();   // previous tile fully consumed
#pragma unroll
    for (int i = 0; i < 4; i++) {
      const int c = (w << 2) | i;
      const int tm = c >> 1, kk = c & 1;
      const int krow = k0 + kk * 32 + quad * 8;
      // A chunk
      const unsigned short* ga = A + (size_t)(m0 + tm * 16 + l16) * K + krow;
      __builtin_amdgcn_global_load_lds((const __attribute__((address_space(1))) void*)ga,
          (__attribute__((address_space(3))) void*)&As[c * 512], 16, 0, 0);
      // B chunk
      const int prow = p0 + tm * 16 + l16;
      const unsigned short* gb;
      if (!CONCAT || krow < K1)
        gb = B1 + ((((size_t)n << 14) + prow) * (size_t)K1) + krow;
      else
        gb = B2 + ((((size_t)n << 14) + prow) * (size_t)K2) + (krow - K1);
      __builtin_amdgcn_global_load_lds((const __attribute__((address_space(1))) void*)gb,
          (__attribute__((address_space(3))) void*)&Bs[c * 512], 16, 0, 0);
    }
    __syncthreads();
#pragma unroll
    for (int kk = 0; kk < 2; kk++) {
      short8 af[4], bfr[4];
#pragma unroll
      for (int im = 0; im < 4; im++)
        af[im] = *(const short8*)&As[(((wm * 4 + im) * 2 + kk) * 64 + lane) * 8];
#pragma unroll
      for (int in = 0; in < 4; in++)
        bfr[in] = *(const short8*)&Bs[(((wn * 4 + in) * 2 + kk) * 64 + lane) * 8];
#pragma unroll
      for (int im = 0; im < 4; im++)
#pragma unroll
        for (int in = 0; in < 4; in++)
          acc[im][in] = __builtin_amdgcn_mfma_f32_16x16x32_bf16(af[im], bfr[in], acc[im][in], 0, 0, 0);
    }
  }

  // epilogue: D[row=o=quad*4+reg][col=p=lane&15]; pack 4 o as ushort4
  const size_t nb = ((size_t)n << 14);
#pragma unroll
  for (int im = 0; im < 4; im++) {
    const int om = m0 + (wm * 4 + im) * 16 + quad * 4;
    const f32x4 bv = *(const f32x4*)(bias + om);
#pragma unroll
    for (int in = 0; in < 4; in++) {
      const int p = p0 + (wn * 4 + in) * 16 + l16;
      float v0 = acc[im][in].x + bv.x;
      float v1 = acc[im][in].y + bv.y;
      float v2 = acc[im][in].z + bv.z;
      float v3 = acc[im][in].w + bv.w;
      if (GELU) { v0 = gelu_f(v0); v1 = gelu_f(v1); v2 = gelu_f(v2); v3 = gelu_f(v3); }
      us4 o4;
      o4.x = f2bf(v0); o4.y = f2bf(v1); o4.z = f2bf(v2); o4.w = f2bf(v3);
      *(us4*)&Y[(nb + p) * M + om] = o4;
    }
  }
}

// ------------------------------------------------------------- cluster
// NHWC y bf16 [n][p][512] -> nx bf16 [n][p][256]. One block per m.
__global__ __launch_bounds__(256) void cluster_kernel(
    const unsigned short* __restrict__ y, const float* __restrict__ alpha_p,
    const float* __restrict__ beta_p, unsigned short* __restrict__ nx) {
  const int m = blockIdx.x;
  const int n = m >> 5, f = (m >> 2) & 7, s1 = (m >> 1) & 1, s2 = m & 1;
  const int t = threadIdx.x;
  const float alpha = alpha_p[0], beta = beta_p[0];

  __shared__ float cs[64][68];          // [b][cc]
  __shared__ float cpn[64][36];         // [b][cc<32] l2-normed point centers
  __shared__ float acc[64][33];         // accumulators + weight-count
  __shared__ float svals[4096];
  __shared__ unsigned char sbest[4096];

  const size_t nbase = ((size_t)n << 14);
  const int prow0 = s1 * 64, pcol0 = s2 * 64;
  const int ch0 = f * 64;

  // ---- phase 1: 8x8 block means. thread: b=t>>2 (block), g=t&3 (16 ch)
  {
    const int b = t >> 2, g = t & 3;
    const int pr0 = prow0 + (b >> 3) * 8, pc0 = pcol0 + (b & 7) * 8;
    float a16[16];
#pragma unroll
    for (int j = 0; j < 16; j++) a16[j] = 0.f;
#pragma unroll 1
    for (int r = 0; r < 8; r++) {
#pragma unroll
      for (int cc = 0; cc < 8; cc++) {
        const int p = (pr0 + r) * 128 + pc0 + cc;
        const unsigned short* yp = y + (nbase + p) * 512 + ch0 + g * 16;
        const us8 v0 = *(const us8*)yp;
        const us8 v1 = *(const us8*)(yp + 8);
#pragma unroll
        for (int j = 0; j < 8; j++) { a16[j] += bf2f(v0[j]); a16[8 + j] += bf2f(v1[j]); }
      }
    }
#pragma unroll
    for (int j = 0; j < 16; j++) cs[b][g * 16 + j] = a16[j] * (1.f / 64.f);
  }
  __syncthreads();

  // ---- phase 1b
  if (t < 64) {
    const int b = t;
    float s = 0.f;
#pragma unroll
    for (int cc = 0; cc < 32; cc++) { float v = cs[b][cc]; s = fmaf(v, v, s); }
    float inv = 1.f / fmaxf(sqrtf(s), 1e-12f);
#pragma unroll
    for (int cc = 0; cc < 32; cc++) cpn[b][cc] = cs[b][cc] * inv;
#pragma unroll
    for (int q = 0; q < 32; q++) acc[b][q] = cs[b][32 + q];
    acc[b][32] = 1.f;
  }
  __syncthreads();

  // ---- phase 2: best center + weighted scatter (2 points/thread/iter)
#pragma unroll 1
  for (int g = 0; g < 8; g++) {
    const int la = g * 512 + t;
    const int lb = la + 256;
    const int pa = (prow0 + (la >> 6)) * 128 + pcol0 + (la & 63);
    const int pb = (prow0 + (lb >> 6)) * 128 + pcol0 + (lb & 63);
    const unsigned short* ya = y + (nbase + pa) * 512 + ch0;
    const unsigned short* yb = y + (nbase + pb) * 512 + ch0;
    float xpa[32], xpb[32];
#pragma unroll
    for (int q8 = 0; q8 < 4; q8++) {
      const us8 va = *(const us8*)(ya + q8 * 8);
      const us8 vb = *(const us8*)(yb + q8 * 8);
#pragma unroll
      for (int j = 0; j < 8; j++) { xpa[q8 * 8 + j] = bf2f(va[j]); xpb[q8 * 8 + j] = bf2f(vb[j]); }
    }
    float na = 0.f, nbv = 0.f;
#pragma unroll
    for (int cc = 0; cc < 32; cc++) {
      na = fmaf(xpa[cc], xpa[cc], na);
      nbv = fmaf(xpb[cc], xpb[cc], nbv);
    }
    const float inva = 1.f / fmaxf(sqrtf(na), 1e-12f);
    const float invb = 1.f / fmaxf(sqrtf(nbv), 1e-12f);
    float zma = -1e30f, zmb = -1e30f;
    int bba = 0, bbb = 0;
    for (int b = 0; b < 64; b++) {
      float da = 0.f, db = 0.f;
#pragma unroll
      for (int c4 = 0; c4 < 32; c4 += 4) {
        const float4 cp = *(const float4*)&cpn[b][c4];
        da = fmaf(xpa[c4], cp.x, da); da = fmaf(xpa[c4 + 1], cp.y, da);
        da = fmaf(xpa[c4 + 2], cp.z, da); da = fmaf(xpa[c4 + 3], cp.w, da);
        db = fmaf(xpb[c4], cp.x, db); db = fmaf(xpb[c4 + 1], cp.y, db);
        db = fmaf(xpb[c4 + 2], cp.z, db); db = fmaf(xpb[c4 + 3], cp.w, db);
      }
      const float za = fmaf(alpha, da * inva, beta);
      const float zb = fmaf(alpha, db * invb, beta);
      if (za > zma) { zma = za; bba = b; }
      if (zb > zmb) { zmb = zb; bbb = b; }
    }
    const float va = 1.f / (1.f + __expf(-zma));
    const float vb = 1.f / (1.f + __expf(-zmb));
    svals[la] = va; sbest[la] = (unsigned char)bba;
    svals[lb] = vb; sbest[lb] = (unsigned char)bbb;
#pragma unroll
    for (int q8 = 0; q8 < 4; q8++) {
      const us8 wa = *(const us8*)(ya + 32 + q8 * 8);
      const us8 wb = *(const us8*)(yb + 32 + q8 * 8);
#pragma unroll
      for (int j = 0; j < 8; j++) {
        atomicAdd(&acc[bba][q8 * 8 + j], va * bf2f(wa[j]));
        atomicAdd(&acc[bbb][q8 * 8 + j], vb * bf2f(wb[j]));
      }
    }
    atomicAdd(&acc[bba][32], va);
    atomicAdd(&acc[bbb][32], vb);
  }
  __syncthreads();

  // ---- phase 3: means
  for (int idx = t; idx < 2048; idx += 256) {
    const int b = idx >> 5, q = idx & 31;
    acc[b][q] = acc[b][q] / acc[b][32];
  }
  __syncthreads();

  // ---- phase 4: gather -> nx NHWC (32 contiguous ch at f*32)
#pragma unroll 1
  for (int i = 0; i < 16; i++) {
    const int l = i * 256 + t;
    const int p = (prow0 + (l >> 6)) * 128 + pcol0 + (l & 63);
    const float v = svals[l];
    const int b = sbest[l];
    unsigned short* nr = nx + (nbase + p) * 256 + f * 32;
#pragma unroll
    for (int q8 = 0; q8 < 4; q8++) {
      us8 o;
#pragma unroll
      for (int j = 0; j < 8; j++) o[j] = f2bf(v * acc[b][q8 * 8 + j]);
      *(us8*)&nr[q8 * 8] = o;
    }
  }
}

// ------------------------------------------------- groupnorm reduce (bf16)
__global__ __launch_bounds__(256) void gn_reduce_bf16(const unsigned short* __restrict__ v,
                                                      float* __restrict__ sums) {
  const int n = blockIdx.y;
  const us8* base = (const us8*)(v + ((size_t)n << 22));
  float s = 0.f, s2 = 0.f;
  for (int i = blockIdx.x * 256 + threadIdx.x; i < (1 << 19); i += 64 * 256) {
    const us8 x = base[i];
#pragma unroll
    for (int j = 0; j < 8; j++) {
      const float f = bf2f(x[j]);
      s += f;
      s2 = fmaf(f, f, s2);
    }
  }
  for (int off = 32; off > 0; off >>= 1) {
    s += __shfl_down(s, off);
    s2 += __shfl_down(s2, off);
  }
  __shared__ float ws1[4], ws2[4];
  const int wid = threadIdx.x >> 6, lanei = threadIdx.x & 63;
  if (lanei == 0) { ws1[wid] = s; ws2[wid] = s2; }
  __syncthreads();
  if (threadIdx.x == 0) {
    atomicAdd(&sums[2 * n],     ws1[0] + ws1[1] + ws1[2] + ws1[3]);
    atomicAdd(&sums[2 * n + 1], ws2[0] + ws2[1] + ws2[2] + ws2[3]);
  }
}

// ------------------------------------- GN0 affine, in-place on bf16 NHWC
__global__ __launch_bounds__(256) void gn0_affine(unsigned short* __restrict__ v,
                                                  const float* __restrict__ sums,
                                                  const float* __restrict__ g0w,
                                                  const float* __restrict__ g0b) {
  const int i = blockIdx.x * 256 + threadIdx.x;   // us8 chunk id, 1<<22 total
  const int n = i >> 19;
  const int cb = (i & 31) * 8;
  const float cntinv = 1.f / (float)(CIN * PIX);
  const float mu = sums[2 * n] * cntinv;
  const float var = sums[2 * n + 1] * cntinv - mu * mu;
  const float rs = rsqrtf(var + 1e-5f);
  us8* p = (us8*)v + i;
  const us8 x = *p;
  us8 o;
#pragma unroll
  for (int j = 0; j < 8; j++) {
    const float a = rs * g0w[cb + j];
    const float b = g0b[cb + j] - mu * a;
    o[j] = f2bf(fmaf(bf2f(x[j]), a, b));
  }
  *p = o;
}

// ------------------- final: GN1 affine + layer_scale + residual, NHWC->NCHW
__global__ __launch_bounds__(256) void final_transpose(
    const unsigned short* __restrict__ u, const float* __restrict__ x,
    const float* __restrict__ sums, const float* __restrict__ g1w,
    const float* __restrict__ g1b, const float* __restrict__ lsc,
    float* __restrict__ out) {
  __shared__ float tile[64][68];
  const int t = threadIdx.x;
  const int p0 = blockIdx.x * 64, c0 = blockIdx.y * 64, n = blockIdx.z;
  {
    const int pl = t >> 2, g = t & 3;
    const unsigned short* up = u + ((((size_t)n << 14) + p0 + pl) << 8) + c0 + g * 16;
    const us8 v0 = *(const us8*)up;
    const us8 v1 = *(const us8*)(up + 8);
#pragma unroll
    for (int j = 0; j < 8; j++) {
      tile[pl][g * 16 + j] = bf2f(v0[j]);
      tile[pl][g * 16 + 8 + j] = bf2f(v1[j]);
    }
  }
  __syncthreads();
  {
    const int cl = t >> 2, g = t & 3;
    const int c = c0 + cl;
    const float cntinv = 1.f / (float)(CIN * PIX);
    const float mu = sums[2 * n] * cntinv;
    const float var = sums[2 * n + 1] * cntinv - mu * mu;
    const float rs = rsqrtf(var + 1e-5f);
    const float gw = rs * g1w[c] * lsc[c];
    const float gb = (g1b[c] - mu * rs * g1w[c]) * lsc[c];
    const size_t rowb = ((size_t)(n * 256 + c) << 14) + p0 + g * 16;
#pragma unroll
    for (int q = 0; q < 4; q++) {
      const float4 xv = *(const float4*)(x + rowb + q * 4);
      float4 o;
      o.x = fmaf(tile[g * 16 + q * 4][cl], gw, gb) + xv.x;
      o.y = fmaf(tile[g * 16 + q * 4 + 1][cl], gw, gb) + xv.y;
      o.z = fmaf(tile[g * 16 + q * 4 + 2][cl], gw, gb) + xv.z;
      o.w = fmaf(tile[g * 16 + q * 4 + 3][cl], gw, gb) + xv.w;
      *(float4*)(out + rowb + q * 4) = o;
    }
  }
}

// ---------------------------------------------------------------- launch
extern "C" void kernel_launch(void* const* d_in, const int* in_sizes, int n_in,
                              void* d_out, int out_size, void* d_ws, size_t ws_size,
                              hipStream_t stream) {
  const float* x       = (const float*)d_in[0];
  const float* proj_w  = (const float*)d_in[1];
  const float* proj_b  = (const float*)d_in[2];
  const float* merge_w = (const float*)d_in[3];
  const float* merge_b = (const float*)d_in[4];
  const float* alpha   = (const float*)d_in[5];
  const float* beta    = (const float*)d_in[6];
  const float* g0w     = (const float*)d_in[7];
  const float* g0b     = (const float*)d_in[8];
  const float* w0      = (const float*)d_in[9];
  const float* b0      = (const float*)d_in[10];
  const float* w1      = (const float*)d_in[11];
  const float* b1      = (const float*)d_in[12];
  const float* g1w     = (const float*)d_in[13];
  const float* g1b     = (const float*)d_in[14];
  const float* lsc     = (const float*)d_in[15];
  float* out = (float*)d_out;

  // workspace (ushort units), ~270 MB total; newx scratch lives in d_out
  unsigned short* wsu = (unsigned short*)d_ws;
  unsigned short* xT  = wsu;                      // 8*16384*256
  unsigned short* y   = xT + (size_t)33554432;    // 8*16384*512 (reused as h)
  unsigned short* nx  = y + (size_t)67108864;     // 8*16384*256 (reused as u)
  unsigned short* pw  = nx + (size_t)33554432;    // 512*256
  unsigned short* mw  = pw + 131072;              // 256*256
  unsigned short* w0t = mw + 65536;               // 512*512
  unsigned short* w1t = w0t + 262144;             // 256*512
  float* sums = (float*)(w1t + 131072);           // 32 floats
  unsigned short* newx = (unsigned short*)d_out;  // 67 MB scratch inside out

  zero_kernel<<<1, 64, 0, stream>>>(sums, 32);
  prep_weights<<<2304, 256, 0, stream>>>(proj_w, merge_w, w0, w1, pw, mw, w0t, w1t);
  x_to_nhwc<<<dim3(256, 4, NB), 256, 0, stream>>>(x, xT);

  // proj: y[n][p][512] = pw @ xT
  mfma_gemm<false, false><<<dim3(128, 4, NB), 256, 0, stream>>>(
      pw, proj_b, xT, nullptr, y, 512, 256, 256);

  // cluster
  cluster_kernel<<<256, 256, 0, stream>>>(y, alpha, beta, nx);

  // merge: newx[n][p][256] = mw @ nx
  mfma_gemm<false, false><<<dim3(128, 2, NB), 256, 0, stream>>>(
      mw, merge_b, nx, nullptr, newx, 256, 256, 256);

  // GN0 stats + in-place affine
  gn_reduce_bf16<<<dim3(64, NB), 256, 0, stream>>>(newx, sums);
  gn0_affine<<<16384, 256, 0, stream>>>(newx, sums, g0w, g0b);

  // MLP0: h = gelu(w0t @ [xT ; newx]) (h reuses y)
  mfma_gemm<true, true><<<dim3(128, 4, NB), 256, 0, stream>>>(
      w0t, b0, xT, newx, y, 512, 512, 256);

  // MLP1: u = w1t @ h (u reuses nx)
  mfma_gemm<false, false><<<dim3(128, 2, NB), 256, 0, stream>>>(
      w1t, b1, y, nullptr, nx, 256, 512, 512);

  // GN1 stats + final transpose/residual
  gn_reduce_bf16<<<dim3(64, NB), 256, 0, stream>>>(nx, sums + 16);
  final_transpose<<<dim3(256, 4, NB), 256, 0, stream>>>(
      nx, x, sums + 16, g1w, g1b, lsc, out);
}

// Round 4
// 1006.143 us; speedup vs baseline: 2.5410x; 1.0739x over previous
//
#include <hip/hip_runtime.h>
#include <math.h>

#define PIX   16384       // H*W
#define NB    8
#define CIN   256

typedef __attribute__((ext_vector_type(8))) short    short8;   // bf16x8 frag (4 VGPR)
typedef __attribute__((ext_vector_type(4))) float    f32x4;
typedef __attribute__((ext_vector_type(4))) unsigned short us4;
typedef __attribute__((ext_vector_type(8))) unsigned short us8;

__device__ __forceinline__ float bf2f(unsigned short h) {
  return __uint_as_float(((unsigned int)h) << 16);
}
__device__ __forceinline__ unsigned short f2bf(float f) {  // round-nearest-even
  unsigned int u = __float_as_uint(f);
  return (unsigned short)((u + 0x7FFFu + ((u >> 16) & 1u)) >> 16);
}
__device__ __forceinline__ float gelu_f(float v) {
  return 0.5f * v * (1.f + erff(v * 0.70710678118654752f));
}

// ---------------------------------------------------------------- zero
__global__ void zero_kernel(float* p, int n) {
  int i = blockIdx.x * blockDim.x + threadIdx.x;
  if (i < n) p[i] = 0.f;
}

// ---------------------------------------------------- weight prep (bf16)
__global__ void prep_weights(const float* __restrict__ pw_f, const float* __restrict__ mw_f,
                             const float* __restrict__ w0, const float* __restrict__ w1,
                             unsigned short* __restrict__ pw, unsigned short* __restrict__ mw,
                             unsigned short* __restrict__ w0t, unsigned short* __restrict__ w1t) {
  const int S1 = 512 * 256, S2 = 256 * 256, S3 = 512 * 512, S4 = 256 * 512;
  int i = blockIdx.x * 256 + threadIdx.x;
  if (i < S1) { pw[i] = f2bf(pw_f[i]); return; }
  i -= S1;
  if (i < S2) { mw[i] = f2bf(mw_f[i]); return; }
  i -= S2;
  if (i < S3) { int o = i >> 9, k = i & 511; w0t[i] = f2bf(w0[k * 512 + o]); return; }
  i -= S3;
  if (i < S4) { int o = i >> 9, k = i & 511; w1t[i] = f2bf(w1[k * 256 + o]); }
}

// ------------------------------------------- x: NCHW fp32 -> NHWC bf16
__global__ __launch_bounds__(256) void x_to_nhwc(const float* __restrict__ x,
                                                 unsigned short* __restrict__ xT) {
  __shared__ float tile[64][65];
  const int t = threadIdx.x;
  const int p0 = blockIdx.x * 64, c0 = blockIdx.y * 64, n = blockIdx.z;
#pragma unroll
  for (int i = 0; i < 4; i++) {
    const int c = i * 16 + (t >> 4);
    const float4 v = *(const float4*)(x + ((size_t)(n * 256 + c0 + c) << 14) + p0 + (t & 15) * 4);
    tile[c][(t & 15) * 4]     = v.x;
    tile[c][(t & 15) * 4 + 1] = v.y;
    tile[c][(t & 15) * 4 + 2] = v.z;
    tile[c][(t & 15) * 4 + 3] = v.w;
  }
  __syncthreads();
#pragma unroll
  for (int i = 0; i < 4; i++) {
    const int pp = i * 16 + (t >> 4);
    const int cl = (t & 15) * 4;
    us4 o;
    o.x = f2bf(tile[cl][pp]); o.y = f2bf(tile[cl + 1][pp]);
    o.z = f2bf(tile[cl + 2][pp]); o.w = f2bf(tile[cl + 3][pp]);
    *(us4*)&xT[(((size_t)n << 14) + p0 + pp) * 256 + c0 + cl] = o;
  }
}

// ---------------------------------------------------------- MFMA GEMM
// Y[n][p][o] = sum_k A[o][k] * B[n][p][k] + bias[o]  (optional gelu)
// astride/bstride: per-image A and bias offsets (elements). STATS: block-wise
// fp32 sum/sumsq of outputs (pre-round) atomically added to sums[2n],[2n+1].
template<bool CONCAT, bool GELU, bool STATS>
__global__ __launch_bounds__(256, 2) void mfma_gemm(
    const unsigned short* __restrict__ A, const float* __restrict__ bias,
    const unsigned short* __restrict__ B1, const unsigned short* __restrict__ B2,
    unsigned short* __restrict__ Y, int M, int K, int K1,
    int astride, int bstride, float* __restrict__ sums) {
  __shared__ unsigned short As[8192];
  __shared__ unsigned short Bs[8192];
  __shared__ float r1[4], r2[4];
  const int t = threadIdx.x;
  const int lane = t & 63, w = t >> 6;
  const int quad = lane >> 4, l16 = lane & 15;
  const int p0 = blockIdx.x * 128, m0 = blockIdx.y * 128;
  const int n = blockIdx.z;
  const int wm = w & 1, wn = w >> 1;
  const int K2 = K - K1;

  A += (size_t)n * astride;

  f32x4 acc[4][4];
#pragma unroll
  for (int im = 0; im < 4; im++)
#pragma unroll
    for (int in = 0; in < 4; in++) acc[im][in] = (f32x4)0.f;

  for (int k0 = 0; k0 < K; k0 += 64) {
    __syncthreads();
#pragma unroll
    for (int i = 0; i < 4; i++) {
      const int c = (w << 2) | i;
      const int tm = c >> 1, kk = c & 1;
      const int krow = k0 + kk * 32 + quad * 8;
      const unsigned short* ga = A + (size_t)(m0 + tm * 16 + l16) * K + krow;
      __builtin_amdgcn_global_load_lds((const __attribute__((address_space(1))) void*)ga,
          (__attribute__((address_space(3))) void*)&As[c * 512], 16, 0, 0);
      const int prow = p0 + tm * 16 + l16;
      const unsigned short* gb;
      if (!CONCAT || krow < K1)
        gb = B1 + ((((size_t)n << 14) + prow) * (size_t)K1) + krow;
      else
        gb = B2 + ((((size_t)n << 14) + prow) * (size_t)K2) + (krow - K1);
      __builtin_amdgcn_global_load_lds((const __attribute__((address_space(1))) void*)gb,
          (__attribute__((address_space(3))) void*)&Bs[c * 512], 16, 0, 0);
    }
    __syncthreads();
#pragma unroll
    for (int kk = 0; kk < 2; kk++) {
      short8 af[4], bfr[4];
#pragma unroll
      for (int im = 0; im < 4; im++)
        af[im] = *(const short8*)&As[(((wm * 4 + im) * 2 + kk) * 64 + lane) * 8];
#pragma unroll
      for (int in = 0; in < 4; in++)
        bfr[in] = *(const short8*)&Bs[(((wn * 4 + in) * 2 + kk) * 64 + lane) * 8];
#pragma unroll
      for (int im = 0; im < 4; im++)
#pragma unroll
        for (int in = 0; in < 4; in++)
          acc[im][in] = __builtin_amdgcn_mfma_f32_16x16x32_bf16(af[im], bfr[in], acc[im][in], 0, 0, 0);
    }
  }

  const size_t nb = ((size_t)n << 14);
  float s = 0.f, s2 = 0.f;
#pragma unroll
  for (int im = 0; im < 4; im++) {
    const int om = m0 + (wm * 4 + im) * 16 + quad * 4;
    const f32x4 bv = *(const f32x4*)(bias + (size_t)n * bstride + om);
#pragma unroll
    for (int in = 0; in < 4; in++) {
      const int p = p0 + (wn * 4 + in) * 16 + l16;
      float v0 = acc[im][in].x + bv.x;
      float v1 = acc[im][in].y + bv.y;
      float v2 = acc[im][in].z + bv.z;
      float v3 = acc[im][in].w + bv.w;
      if (GELU) { v0 = gelu_f(v0); v1 = gelu_f(v1); v2 = gelu_f(v2); v3 = gelu_f(v3); }
      if (STATS) {
        s += (v0 + v1) + (v2 + v3);
        s2 = fmaf(v0, v0, s2); s2 = fmaf(v1, v1, s2);
        s2 = fmaf(v2, v2, s2); s2 = fmaf(v3, v3, s2);
      }
      us4 o4;
      o4.x = f2bf(v0); o4.y = f2bf(v1); o4.z = f2bf(v2); o4.w = f2bf(v3);
      *(us4*)&Y[(nb + p) * M + om] = o4;
    }
  }
  if (STATS) {
#pragma unroll
    for (int off = 32; off > 0; off >>= 1) {
      s += __shfl_down(s, off);
      s2 += __shfl_down(s2, off);
    }
    if (lane == 0) { r1[w] = s; r2[w] = s2; }
    __syncthreads();
    if (t == 0) {
      atomicAdd(&sums[2 * n],     (r1[0] + r1[1]) + (r1[2] + r1[3]));
      atomicAdd(&sums[2 * n + 1], (r2[0] + r2[1]) + (r2[2] + r2[3]));
    }
  }
}

// ------------------------------------------------------------- cluster
// NHWC y bf16 [n][p][512] -> nx bf16 [n][p][256]. One block (1024 thr) per m.
// Sim via MFMA: A-frag = point channels (direct global load in frag layout),
// B-frag = bf16 l2-normed centers (LDS). Argmax: shuffle butterfly + bpermute.
__global__ __launch_bounds__(1024) void cluster_kernel(
    const unsigned short* __restrict__ y, const float* __restrict__ alpha_p,
    const float* __restrict__ beta_p, unsigned short* __restrict__ nx) {
  const int m = blockIdx.x;
  const int n = m >> 5, f = (m >> 2) & 7, s1 = (m >> 1) & 1, s2 = m & 1;
  const int t = threadIdx.x;
  const int wave = t >> 6, lane = t & 63;
  const int quad = lane >> 4, l16 = lane & 15;
  const float alpha = alpha_p[0], beta = beta_p[0];

  __shared__ float cs[64][68];             // [b][cc] center means
  __shared__ unsigned short cpnh[64][32];  // bf16 normalized point-centers
  __shared__ float accv[64][36];           // [b][0..31]=val acc, [32]=count
  __shared__ float svals[4096];
  __shared__ unsigned char sbest[4096];

  const size_t nbase = ((size_t)n << 14);
  const int prow0 = s1 * 64, pcol0 = s2 * 64;
  const int ch0 = f * 64;

  // ---- phase 1: 8x8 block means. thread: b=t>>4, 4 ch at (t&15)*4
  {
    const int b = t >> 4, g = t & 15;
    const int pr0 = prow0 + (b >> 3) * 8, pc0 = pcol0 + (b & 7) * 8;
    float a4[4] = {0.f, 0.f, 0.f, 0.f};
#pragma unroll 1
    for (int r = 0; r < 8; r++) {
#pragma unroll
      for (int cc = 0; cc < 8; cc++) {
        const us4 v = *(const us4*)(y + (nbase + (size_t)(pr0 + r) * 128 + pc0 + cc) * 512 + ch0 + g * 4);
        a4[0] += bf2f(v.x); a4[1] += bf2f(v.y); a4[2] += bf2f(v.z); a4[3] += bf2f(v.w);
      }
    }
#pragma unroll
    for (int j = 0; j < 4; j++) cs[b][g * 4 + j] = a4[j] * (1.f / 64.f);
  }
  __syncthreads();

  // ---- phase 1b: normalize point half -> bf16, init accumulators
  if (t < 64) {
    const int b = t;
    float s = 0.f;
#pragma unroll
    for (int cc = 0; cc < 32; cc++) { float v = cs[b][cc]; s = fmaf(v, v, s); }
    const float inv = 1.f / fmaxf(sqrtf(s), 1e-12f);
#pragma unroll
    for (int cc = 0; cc < 32; cc++) cpnh[b][cc] = f2bf(cs[b][cc] * inv);
#pragma unroll
    for (int q = 0; q < 32; q++) accv[b][q] = cs[b][32 + q];
    accv[b][32] = 1.f;
  }
  __syncthreads();

  // ---- phase 2: per-wave tiles of 16 points; MFMA sim + argmax + scatter
#pragma unroll 1
  for (int tile = 0; tile < 16; tile++) {
    const int pidx = wave * 256 + tile * 16;             // point base
    const int pix = (prow0 + (pidx >> 6)) * 128 + pcol0 + (pidx & 63) + l16;
    const unsigned short* yp = y + (nbase + pix) * 512 + ch0;
    const short8 apt = *(const short8*)(yp + quad * 8);        // point A-frag
    const short8 avl = *(const short8*)(yp + 32 + quad * 8);   // value half

    // ||x_point|| for point l16 (sum partial squares across quads)
    float nrm = 0.f;
#pragma unroll
    for (int j = 0; j < 8; j++) {
      const float fv = bf2f((unsigned short)apt[j]);
      nrm = fmaf(fv, fv, nrm);
    }
    nrm += __shfl_xor(nrm, 16);
    nrm += __shfl_xor(nrm, 32);
    const float inva = 1.f / fmaxf(sqrtf(nrm), 1e-12f);

    // 4 MFMAs: dots vs center groups g*16..g*16+15
    f32x4 d[4];
#pragma unroll
    for (int g = 0; g < 4; g++) {
      const short8 bfr = *(const short8*)&cpnh[g * 16 + l16][quad * 8];
      d[g] = __builtin_amdgcn_mfma_f32_16x16x32_bf16(apt, bfr, (f32x4)0.f, 0, 0, 0);
    }

    // per-reg fold over groups (rows = points quad*4+r, col = l16)
    float bv[4]; int bi[4];
#pragma unroll
    for (int r = 0; r < 4; r++) {
      bv[r] = d[0][r]; bi[r] = l16;
#pragma unroll
      for (int g = 1; g < 4; g++) {
        const float c = d[g][r];
        if (c > bv[r]) { bv[r] = c; bi[r] = g * 16 + l16; }
      }
    }
    // butterfly max over the 16 cols (lane bits 0..3), tie -> smaller idx
#pragma unroll
    for (int r = 0; r < 4; r++) {
#pragma unroll
      for (int msk = 1; msk < 16; msk <<= 1) {
        const float v2 = __shfl_xor(bv[r], msk);
        const int   i2 = __shfl_xor(bi[r], msk);
        if (v2 > bv[r] || (v2 == bv[r] && i2 < bi[r])) { bv[r] = v2; bi[r] = i2; }
      }
    }
    // lane (quad,l16) now holds rows quad*4+r. Re-distribute: this lane takes
    // responsibility for row quad*4+(l16&3); then bpermute row l16 from lane
    // ((l16>>2)*16 + (l16&3)).
    const float rv01 = (l16 & 1) ? bv[1] : bv[0];
    const float rv23 = (l16 & 1) ? bv[3] : bv[2];
    const float rowv = (l16 & 2) ? rv23 : rv01;
    const int   ri01 = (l16 & 1) ? bi[1] : bi[0];
    const int   ri23 = (l16 & 1) ? bi[3] : bi[2];
    const int   rowi = (l16 & 2) ? ri23 : ri01;
    const int sl4 = (((l16 >> 2) << 4) | (l16 & 3)) << 2;
    const float dot = __int_as_float(__builtin_amdgcn_ds_bpermute(sl4, __float_as_int(rowv)));
    const int   idx = __builtin_amdgcn_ds_bpermute(sl4, rowi);

    const float val = 1.f / (1.f + __expf(-fmaf(alpha, dot * inva, beta)));
    if (quad == 0) {
      svals[pidx + l16] = val;
      sbest[pidx + l16] = (unsigned char)idx;
    }
#pragma unroll
    for (int j = 0; j < 8; j++)
      atomicAdd(&accv[idx][quad * 8 + j], val * bf2f((unsigned short)avl[j]));
    if (quad == 0) atomicAdd(&accv[idx][32], val);
  }
  __syncthreads();

  // ---- phase 3: cluster means
  for (int i = t; i < 2048; i += 1024) {
    const int b = i >> 5, q = i & 31;
    accv[b][q] = accv[b][q] / accv[b][32];
  }
  __syncthreads();

  // ---- phase 4: gather -> nx NHWC (32 contiguous ch at f*32)
#pragma unroll
  for (int i = 0; i < 4; i++) {
    const int l = i * 1024 + t;
    const int p = (prow0 + (l >> 6)) * 128 + pcol0 + (l & 63);
    const float v = svals[l];
    const int b = sbest[l];
    unsigned short* nr = nx + (nbase + p) * 256 + f * 32;
#pragma unroll
    for (int q8 = 0; q8 < 4; q8++) {
      us8 o;
#pragma unroll
      for (int j = 0; j < 8; j++) o[j] = f2bf(v * accv[b][q8 * 8 + j]);
      *(us8*)&nr[q8 * 8] = o;
    }
  }
}

// ---------------- GN0 per-(n,c) affine coefficients from fused sums
__global__ void gn_finalize0(const float* __restrict__ sums, const float* __restrict__ g0w,
                             const float* __restrict__ g0b, float* __restrict__ scl,
                             float* __restrict__ bia) {
  const int n = blockIdx.x, c = threadIdx.x;
  const float cntinv = 1.f / (float)(CIN * PIX);
  const float mu = sums[2 * n] * cntinv;
  const float var = sums[2 * n + 1] * cntinv - mu * mu;
  const float rs = rsqrtf(var + 1e-5f);
  const float a = rs * g0w[c];
  scl[n * 256 + c] = a;
  bia[n * 256 + c] = g0b[c] - mu * a;
}

// ---------------- fold GN0 scale into MLP0 weights (per image)
__global__ void w0_scale(const unsigned short* __restrict__ w0t,
                         const float* __restrict__ scl, unsigned short* __restrict__ w0s) {
  const int n = blockIdx.y;
  const int i = blockIdx.x * 256 + threadIdx.x;   // 0..262143
  const int k = i & 511;
  unsigned short v = w0t[i];
  if (k >= 256) v = f2bf(bf2f(v) * scl[n * 256 + k - 256]);
  w0s[(size_t)n * 262144 + i] = v;
}

// ---------------- effective MLP0 bias: b0e[n][o] = b0[o] + sum_k W0n[o][k]*bia[n][k]
__global__ void b0_eff(const unsigned short* __restrict__ w0t, const float* __restrict__ b0,
                       const float* __restrict__ bia, float* __restrict__ b0e) {
  const int n = blockIdx.y;
  const int o = blockIdx.x * 256 + threadIdx.x;   // 0..511
  float s = b0[o];
  const unsigned short* wr = w0t + (size_t)o * 512 + 256;
  const float* br = bia + n * 256;
#pragma unroll 4
  for (int k = 0; k < 256; k++) s = fmaf(bf2f(wr[k]), br[k], s);
  b0e[n * 512 + o] = s;
}

// ------------------- final: GN1 affine + layer_scale + residual, NHWC->NCHW
__global__ __launch_bounds__(256) void final_transpose(
    const unsigned short* __restrict__ u, const float* __restrict__ x,
    const float* __restrict__ sums, const float* __restrict__ g1w,
    const float* __restrict__ g1b, const float* __restrict__ lsc,
    float* __restrict__ out) {
  __shared__ float tile[64][68];
  const int t = threadIdx.x;
  const int p0 = blockIdx.x * 64, c0 = blockIdx.y * 64, n = blockIdx.z;
  {
    const int pl = t >> 2, g = t & 3;
    const unsigned short* up = u + ((((size_t)n << 14) + p0 + pl) << 8) + c0 + g * 16;
    const us8 v0 = *(const us8*)up;
    const us8 v1 = *(const us8*)(up + 8);
#pragma unroll
    for (int j = 0; j < 8; j++) {
      tile[pl][g * 16 + j] = bf2f(v0[j]);
      tile[pl][g * 16 + 8 + j] = bf2f(v1[j]);
    }
  }
  __syncthreads();
  {
    const int cl = t >> 2, g = t & 3;
    const int c = c0 + cl;
    const float cntinv = 1.f / (float)(CIN * PIX);
    const float mu = sums[2 * n] * cntinv;
    const float var = sums[2 * n + 1] * cntinv - mu * mu;
    const float rs = rsqrtf(var + 1e-5f);
    const float gw = rs * g1w[c] * lsc[c];
    const float gb = (g1b[c] - mu * rs * g1w[c]) * lsc[c];
    const size_t rowb = ((size_t)(n * 256 + c) << 14) + p0 + g * 16;
#pragma unroll
    for (int q = 0; q < 4; q++) {
      const float4 xv = *(const float4*)(x + rowb + q * 4);
      float4 o;
      o.x = fmaf(tile[g * 16 + q * 4][cl], gw, gb) + xv.x;
      o.y = fmaf(tile[g * 16 + q * 4 + 1][cl], gw, gb) + xv.y;
      o.z = fmaf(tile[g * 16 + q * 4 + 2][cl], gw, gb) + xv.z;
      o.w = fmaf(tile[g * 16 + q * 4 + 3][cl], gw, gb) + xv.w;
      *(float4*)(out + rowb + q * 4) = o;
    }
  }
}

// ---------------------------------------------------------------- launch
extern "C" void kernel_launch(void* const* d_in, const int* in_sizes, int n_in,
                              void* d_out, int out_size, void* d_ws, size_t ws_size,
                              hipStream_t stream) {
  const float* x       = (const float*)d_in[0];
  const float* proj_w  = (const float*)d_in[1];
  const float* proj_b  = (const float*)d_in[2];
  const float* merge_w = (const float*)d_in[3];
  const float* merge_b = (const float*)d_in[4];
  const float* alpha   = (const float*)d_in[5];
  const float* beta    = (const float*)d_in[6];
  const float* g0w     = (const float*)d_in[7];
  const float* g0b     = (const float*)d_in[8];
  const float* w0      = (const float*)d_in[9];
  const float* b0      = (const float*)d_in[10];
  const float* w1      = (const float*)d_in[11];
  const float* b1      = (const float*)d_in[12];
  const float* g1w     = (const float*)d_in[13];
  const float* g1b     = (const float*)d_in[14];
  const float* lsc     = (const float*)d_in[15];
  float* out = (float*)d_out;

  // workspace (ushort units), ~274 MB; newx scratch lives in d_out
  unsigned short* wsu = (unsigned short*)d_ws;
  unsigned short* xT  = wsu;                      // 8*16384*256
  unsigned short* y   = xT + (size_t)33554432;    // 8*16384*512 (reused as h)
  unsigned short* nx  = y + (size_t)67108864;     // 8*16384*256 (reused as u)
  unsigned short* pw  = nx + (size_t)33554432;    // 512*256
  unsigned short* mw  = pw + 131072;              // 256*256
  unsigned short* w0t = mw + 65536;               // 512*512
  unsigned short* w1t = w0t + 262144;             // 256*512
  unsigned short* w0s = w1t + 131072;             // 8*512*512
  float* sums = (float*)(w0s + (size_t)2097152);  // 32
  float* scl0 = sums + 32;                        // 8*256
  float* bia0 = scl0 + 2048;                      // 8*256
  float* b0e  = bia0 + 2048;                      // 8*512
  unsigned short* newx = (unsigned short*)d_out;  // scratch inside out

  zero_kernel<<<1, 64, 0, stream>>>(sums, 32);
  prep_weights<<<2304, 256, 0, stream>>>(proj_w, merge_w, w0, w1, pw, mw, w0t, w1t);
  x_to_nhwc<<<dim3(256, 4, NB), 256, 0, stream>>>(x, xT);

  // proj: y[n][p][512] = pw @ xT
  mfma_gemm<false, false, false><<<dim3(128, 4, NB), 256, 0, stream>>>(
      pw, proj_b, xT, nullptr, y, 512, 256, 256, 0, 0, nullptr);

  // cluster
  cluster_kernel<<<256, 1024, 0, stream>>>(y, alpha, beta, nx);

  // merge: newx = mw @ nx, fused GN0 stats -> sums[0..15]
  mfma_gemm<false, false, true><<<dim3(128, 2, NB), 256, 0, stream>>>(
      mw, merge_b, nx, nullptr, newx, 256, 256, 256, 0, 0, sums);

  // GN0 affine coefficients, folded weights & bias
  gn_finalize0<<<NB, 256, 0, stream>>>(sums, g0w, g0b, scl0, bia0);
  w0_scale<<<dim3(1024, NB), 256, 0, stream>>>(w0t, scl0, w0s);
  b0_eff<<<dim3(2, NB), 256, 0, stream>>>(w0t, b0, bia0, b0e);

  // MLP0: h = gelu(w0s_n @ [xT ; newx] + b0e_n)   (h reuses y)
  mfma_gemm<true, true, false><<<dim3(128, 4, NB), 256, 0, stream>>>(
      w0s, b0e, xT, newx, y, 512, 512, 256, 262144, 512, nullptr);

  // MLP1: u = w1t @ h + b1, fused GN1 stats -> sums[16..31]   (u reuses nx)
  mfma_gemm<false, false, true><<<dim3(128, 2, NB), 256, 0, stream>>>(
      w1t, b1, y, nullptr, nx, 256, 512, 512, 0, 0, sums + 16);

  // final transpose/residual
  final_transpose<<<dim3(256, 4, NB), 256, 0, stream>>>(
      nx, x, sums + 16, g1w, g1b, lsc, out);
}